// Round 5
// baseline (5181.616 us; speedup 1.0000x reference)
//
#include <hip/hip_runtime.h>
#include <hip/hip_bf16.h>
#include <hip/hip_fp16.h>
#include <cstdint>
#include <cstddef>

#define H 256
#define L 128
#define B 512
#define LEVELS 7
#define BH (B * H) // 131072

// d_out layout (flat f32 element offsets), return order:
// root[B,H], internal_states[255,B,H], internal_mask[255,B],
// leaves[L,B,H], leaves_aux[L,B,H], leaves_mask[L,B]
#define OFF_ROOT 0
#define OFF_INT (B * H)
#define OFF_IMASK (OFF_INT + 255 * BH)
#define OFF_LEAVES (OFF_IMASK + 255 * B)
#define OFF_LAUX (OFF_LEAVES + L * BH)
#define OFF_LMASK (OFF_LAUX + L * BH)

typedef unsigned short u16;
typedef __attribute__((ext_vector_type(8))) _Float16 half8;
typedef __attribute__((ext_vector_type(16))) float f32x16;

// Fragment-major plane layout (fp16, per node, B x H):
// tile T = (b>>5)*16 + (hc>>4)  (1 KiB = 64 lanes x 16 B)
// lane  = (b&31) + 32*((hc>>3)&1),  elem = hc&7
// -> matches verified 32x32x16 A-frag: row = lane&31, k-oct = lane>>5.

__device__ __forceinline__ int postorder_pos(int level, int j) {
    int start = 0;
    for (int k = level; k <= LEVELS; ++k) {
        if ((j >> (k - level)) & 1) start += (2 << k) - 1;
    }
    return start + (2 << level) - 2;
}

__device__ __forceinline__ float sigm(float x) { return 1.0f / (1.0f + __expf(-x)); }

__device__ __forceinline__ u16 f2h(float x) {
    _Float16 h = (_Float16)x;
    u16 u;
    __builtin_memcpy(&u, &h, 2);
    return u;
}

// ---------------- gather: leaves, aux, level-0 post-order h, leaf planes ----
__global__ __launch_bounds__(256) void gather_kernel(
    const int* __restrict__ tok, const float* __restrict__ emb,
    const float* __restrict__ emb_aux, float* __restrict__ out,
    u16* __restrict__ spLeaf, int do_split) {
    int row = blockIdx.x * 4 + (threadIdx.x >> 6);
    int f4i = threadIdx.x & 63;
    int l = row >> 9, b = row & 511;
    int t = tok[row];
    float4 e = reinterpret_cast<const float4*>(emb + (size_t)t * H)[f4i];
    float4 ea = reinterpret_cast<const float4*>(emb_aux + (size_t)t * H)[f4i];
    reinterpret_cast<float4*>(out + OFF_LEAVES)[(size_t)row * 64 + f4i] = e;
    reinterpret_cast<float4*>(out + OFF_LAUX)[(size_t)row * 64 + f4i] = ea;
    int pp = postorder_pos(0, l);
    reinterpret_cast<float4*>(out + OFF_INT + (size_t)pp * BH + (size_t)b * H)[f4i] = e;
    if (do_split) {
        int ko = f4i >> 2;
        int lanep = (b & 31) + 32 * ((f4i >> 1) & 1);
        int elem0 = 4 * (f4i & 1);
        ushort4 hv;
        hv.x = f2h(e.x); hv.y = f2h(e.y); hv.z = f2h(e.z); hv.w = f2h(e.w);
        u16* np = spLeaf + (size_t)l * BH +
                  (size_t)(((b >> 5) * 16 + ko) * 512 + lanep * 8 + elem0);
        *reinterpret_cast<ushort4*>(np) = hv;
    }
}

// ---------------- W pre-pack into fragment-major fp16 tiles (+ masks) -------
// Pack layout: [hcb=8][kb=16][tile = gate*2 + ks][lane][8], 1 KiB tiles.
// lane = col_local + 32*oct; k = kb*32 + ks*16 + oct*8 + elem.
__global__ __launch_bounds__(256) void wpack_kernel(const float* __restrict__ W,
                                                    u16* __restrict__ wp,
                                                    float* __restrict__ out) {
    int q = blockIdx.x * 256 + threadIdx.x; // 0 .. 655359, coalesced read
    int k = q / 1280, col = q - k * 1280;
    int gate = col >> 8, hc = col & 255;
    int hcb = hc >> 5, cl = hc & 31;
    int kb = k >> 5, klr = k & 31;
    int ks = klr >> 4, oct = (klr >> 3) & 1, elem = klr & 7;
    size_t off = ((size_t)(hcb * 16 + kb) * 10 + gate * 2 + ks) * 512 +
                 (cl + 32 * oct) * 8 + elem;
    wp[off] = f2h(W[q]);
    if (q < 255 * B) out[OFF_IMASK + q] = 1.0f;
    if (q < L * B) out[OFF_LMASK + q] = 1.0f;
}

// ---------------- fused fp16 32x32x16 MFMA GEMM + LSTM gates ----------------
// 1 wave/block, NO LDS, NO barriers. Wave tile: 64 rows (mf=2) x 160 gate
// cols (nf=5). All operands loaded global->register from fragment-major
// tiles (lane-contiguous dwordx4), 2-deep register double-buffer; compiler
// emits counted vmcnt (AITER-style VMEM<->MFMA interleave).
template <bool PRESPLIT>
__global__ __launch_bounds__(64) void lstm_level_kernel(
    const u16* __restrict__ wp, const float* __restrict__ bias,
    const float* __restrict__ c_prev, float* __restrict__ c_out,
    float* __restrict__ out, int level, const u16* __restrict__ spIn,
    u16* __restrict__ spOut) {
    const int lane = threadIdx.x;
    const int l31 = lane & 31;
    const int lh = lane >> 5;
    const int p = blockIdx.x >> 3;
    const int b0 = (blockIdx.x & 7) * 64;
    const int rg0 = (blockIdx.x & 7) * 2; // 32-row group base
    const int hcb = blockIdx.y;
    const int hc0 = hcb * 32;

    f32x16 acc[2][5];
#pragma unroll
    for (int nf = 0; nf < 5; ++nf) {
        float bv = bias[nf * H + hc0 + l31];
        f32x16 v;
#pragma unroll
        for (int r = 0; r < 16; ++r) v[r] = bv;
        acc[0][nf] = v;
        acc[1][nf] = v;
    }

    const u16* sL = nullptr;
    const u16* sR = nullptr;
    const float* hL = nullptr;
    const float* hR = nullptr;
    if constexpr (PRESPLIT) {
        sL = spIn + (size_t)(2 * p) * BH;
        sR = sL + BH;
    } else {
        hL = out + OFF_INT + (size_t)postorder_pos(level - 1, 2 * p) * BH;
        hR = out + OFF_INT + (size_t)postorder_pos(level - 1, 2 * p + 1) * BH;
    }

    half8 Af[2][2][2]; // [buf][mf][ks]
    half8 Wf[2][5][2]; // [buf][nf][ks]

    auto loadk = [&](int buf, int kb) {
#pragma unroll
        for (int mf = 0; mf < 2; ++mf)
#pragma unroll
            for (int ks = 0; ks < 2; ++ks) {
                if constexpr (PRESPLIT) {
                    const u16* pl = (kb < 8) ? sL : sR;
                    Af[buf][mf][ks] = *reinterpret_cast<const half8*>(
                        pl + (size_t)(((rg0 + mf) * 16 + (kb & 7) * 2 + ks) * 512 +
                                      lane * 8));
                } else {
                    const float* hsrc = (kb < 8) ? hL : hR;
                    const float* s = hsrc + (size_t)(b0 + 32 * mf + l31) * H +
                                     (kb & 7) * 32 + ks * 16 + lh * 8;
                    float4 v0 = *reinterpret_cast<const float4*>(s);
                    float4 v1 = *reinterpret_cast<const float4*>(s + 4);
                    half8 hv;
                    hv[0] = (_Float16)v0.x; hv[1] = (_Float16)v0.y;
                    hv[2] = (_Float16)v0.z; hv[3] = (_Float16)v0.w;
                    hv[4] = (_Float16)v1.x; hv[5] = (_Float16)v1.y;
                    hv[6] = (_Float16)v1.z; hv[7] = (_Float16)v1.w;
                    Af[buf][mf][ks] = hv;
                }
            }
        const u16* wb = wp + ((size_t)(hcb * 16 + kb) * 10) * 512 + lane * 8;
#pragma unroll
        for (int nf = 0; nf < 5; ++nf)
#pragma unroll
            for (int ks = 0; ks < 2; ++ks)
                Wf[buf][nf][ks] = *reinterpret_cast<const half8*>(
                    wb + (size_t)((nf * 2 + ks) * 512));
    };

    loadk(0, 0);
#pragma unroll 2
    for (int kb = 0; kb < 16; ++kb) {
        const int cur = kb & 1;
        if (kb < 15) loadk(cur ^ 1, kb + 1);
#pragma unroll
        for (int ks = 0; ks < 2; ++ks)
#pragma unroll
            for (int nf = 0; nf < 5; ++nf) {
                acc[0][nf] = __builtin_amdgcn_mfma_f32_32x32x16_f16(
                    Af[cur][0][ks], Wf[cur][nf][ks], acc[0][nf], 0, 0, 0);
                acc[1][nf] = __builtin_amdgcn_mfma_f32_32x32x16_f16(
                    Af[cur][1][ks], Wf[cur][nf][ks], acc[1][nf], 0, 0, 0);
            }
    }

    // --- epilogue: gates -> c, h; f32 outputs + fp16 plane for next level ---
    const int pout = postorder_pos(level, p);
    float* __restrict__ hout = out + OFF_INT + (size_t)pout * BH;
    const float* cLb = c_prev ? c_prev + (size_t)(2 * p) * BH : nullptr;
    const float* cRb = c_prev ? c_prev + (size_t)(2 * p + 1) * BH : nullptr;
    float* __restrict__ cob = c_out + (size_t)p * BH;
    u16* __restrict__ soH = spOut ? spOut + (size_t)p * BH : nullptr;
    const int hc = hc0 + l31;
    const int kop = hcb * 2 + (l31 >> 4);
    const int lpp = 32 * ((l31 >> 3) & 1);
    const int elp = l31 & 7;

#pragma unroll
    for (int mf = 0; mf < 2; ++mf) {
#pragma unroll
        for (int r = 0; r < 16; ++r) {
            // verified 32x32 C layout: row = (r&3)+8*(r>>2)+4*lh, col = l31
            const int b = b0 + 32 * mf + 4 * lh + (r & 3) + 8 * (r >> 2);
            float ig = acc[mf][0][r], f1 = acc[mf][1][r], f2 = acc[mf][2][r];
            float og = acc[mf][3][r], ug = acc[mf][4][r];
            float cl = 0.f, cr = 0.f;
            if (c_prev) {
                cl = cLb[(size_t)b * H + hc];
                cr = cRb[(size_t)b * H + hc];
            }
            float c = sigm(ig) * tanhf(ug) + sigm(f1) * cl + sigm(f2) * cr;
            float hval = sigm(og) * tanhf(c);
            cob[(size_t)b * H + hc] = c;
            hout[(size_t)b * H + hc] = hval;
            if (soH) {
                soH[(size_t)((b >> 5) * 16 + kop) * 512 +
                    (size_t)((b & 31) + lpp) * 8 + elp] = f2h(hval);
            }
            if (level == LEVELS) out[OFF_ROOT + (size_t)b * H + hc] = hval;
        }
    }
}

extern "C" void kernel_launch(void* const* d_in, const int* in_sizes, int n_in,
                              void* d_out, int out_size, void* d_ws,
                              size_t ws_size, hipStream_t stream) {
    const int* tok = (const int*)d_in[0];
    const float* emb = (const float*)d_in[1];
    const float* emb_aux = (const float*)d_in[2];
    const float* W = (const float*)d_in[3];
    const float* bias = (const float*)d_in[4];
    float* out = (float*)d_out;

    // ws: cbuf0 | cbuf1 (f32 c ping-pong, 32MB each) | wp (1.31MB fp16 pack)
    //     | spEven (128 planes fp16, 32MB) | spOdd (64 planes, 16MB)
    float* cbuf0 = (float*)d_ws;
    float* cbuf1 = cbuf0 + (size_t)64 * BH;
    u16* wp = (u16*)(cbuf1 + (size_t)64 * BH);
    u16* spEven = wp + (size_t)655360;
    u16* spOdd = spEven + (size_t)128 * BH;
    size_t need = (size_t)((char*)(spOdd + (size_t)64 * BH) - (char*)d_ws);
    const bool presplit = ws_size >= need;

    hipLaunchKernelGGL(wpack_kernel, dim3(2560), dim3(256), 0, stream, W, wp,
                       out);
    hipLaunchKernelGGL(gather_kernel, dim3(L * B / 4), dim3(256), 0, stream,
                       tok, emb, emb_aux, out, spEven, presplit ? 1 : 0);

    for (int level = 1; level <= LEVELS; ++level) {
        int n = L >> level;
        float* c_out = ((level - 1) & 1) ? cbuf1 : cbuf0;
        const float* c_prev =
            (level == 1) ? nullptr : ((level & 1) ? cbuf1 : cbuf0);
        const u16* spIn = (level & 1) ? spEven : spOdd;
        u16* spOutP =
            (level == LEVELS) ? nullptr : ((level & 1) ? spOdd : spEven);
        dim3 grid(8 * n, 8);
        if (presplit) {
            lstm_level_kernel<true><<<grid, dim3(64), 0, stream>>>(
                wp, bias, c_prev, c_out, out, level, spIn, spOutP);
        } else {
            lstm_level_kernel<false><<<grid, dim3(64), 0, stream>>>(
                wp, bias, c_prev, c_out, out, level, nullptr, spOutP);
        }
    }
}

// Round 6
// 352.300 us; speedup vs baseline: 14.7080x; 14.7080x over previous
//
#include <hip/hip_runtime.h>
#include <hip/hip_bf16.h>
#include <hip/hip_fp16.h>
#include <cstdint>
#include <cstddef>

#define H 256
#define L 128
#define B 512
#define LEVELS 7
#define BH (B * H) // 131072

// d_out layout (flat f32 element offsets), return order:
// root[B,H], internal_states[255,B,H], internal_mask[255,B],
// leaves[L,B,H], leaves_aux[L,B,H], leaves_mask[L,B]
#define OFF_ROOT 0
#define OFF_INT (B * H)
#define OFF_IMASK (OFF_INT + 255 * BH)
#define OFF_LEAVES (OFF_IMASK + 255 * B)
#define OFF_LAUX (OFF_LEAVES + L * BH)
#define OFF_LMASK (OFF_LAUX + L * BH)

typedef unsigned short u16;
typedef __attribute__((ext_vector_type(8))) _Float16 half8;
typedef __attribute__((ext_vector_type(16))) float f32x16;

// Fragment-major plane layout (fp16, per node, B x H):
// tile T = (b>>5)*16 + (hc>>4)  (1 KiB = 64 lanes x 16 B)
// lane  = (b&31) + 32*((hc>>3)&1),  elem = hc&7
// -> matches verified 32x32x16 A-frag: row = lane&31, k-oct = lane>>5.

__device__ __forceinline__ int postorder_pos(int level, int j) {
    int start = 0;
    for (int k = level; k <= LEVELS; ++k) {
        if ((j >> (k - level)) & 1) start += (2 << k) - 1;
    }
    return start + (2 << level) - 2;
}

__device__ __forceinline__ float sigm(float x) { return 1.0f / (1.0f + __expf(-x)); }

__device__ __forceinline__ u16 f2h(float x) {
    _Float16 h = (_Float16)x;
    u16 u;
    __builtin_memcpy(&u, &h, 2);
    return u;
}

__device__ __forceinline__ void gload16(const void* g, const void* l) {
    __builtin_amdgcn_global_load_lds(
        (const __attribute__((address_space(1))) void*)g,
        (__attribute__((address_space(3))) void*)l, 16, 0, 0);
}

// ---------------- gather: leaves, aux, level-0 post-order h, leaf planes ----
__global__ __launch_bounds__(256) void gather_kernel(
    const int* __restrict__ tok, const float* __restrict__ emb,
    const float* __restrict__ emb_aux, float* __restrict__ out,
    u16* __restrict__ spLeaf, int do_split) {
    int row = blockIdx.x * 4 + (threadIdx.x >> 6);
    int f4i = threadIdx.x & 63;
    int l = row >> 9, b = row & 511;
    int t = tok[row];
    float4 e = reinterpret_cast<const float4*>(emb + (size_t)t * H)[f4i];
    float4 ea = reinterpret_cast<const float4*>(emb_aux + (size_t)t * H)[f4i];
    reinterpret_cast<float4*>(out + OFF_LEAVES)[(size_t)row * 64 + f4i] = e;
    reinterpret_cast<float4*>(out + OFF_LAUX)[(size_t)row * 64 + f4i] = ea;
    int pp = postorder_pos(0, l);
    reinterpret_cast<float4*>(out + OFF_INT + (size_t)pp * BH + (size_t)b * H)[f4i] = e;
    if (do_split) {
        int ko = f4i >> 2;
        int lanep = (b & 31) + 32 * ((f4i >> 1) & 1);
        int elem0 = 4 * (f4i & 1);
        ushort4 hv;
        hv.x = f2h(e.x); hv.y = f2h(e.y); hv.z = f2h(e.z); hv.w = f2h(e.w);
        u16* np = spLeaf + (size_t)l * BH +
                  (size_t)(((b >> 5) * 16 + ko) * 512 + lanep * 8 + elem0);
        *reinterpret_cast<ushort4*>(np) = hv;
    }
}

// ---------------- W pre-pack into fragment-major fp16 tiles (+ masks) -------
// Pack layout: [hcb=8][kb=16][tile = gate*2 + ks][lane][8], 1 KiB tiles.
// lane = col_local + 32*oct; k = kb*32 + ks*16 + oct*8 + elem.
__global__ __launch_bounds__(256) void wpack_kernel(const float* __restrict__ W,
                                                    u16* __restrict__ wp,
                                                    float* __restrict__ out) {
    int q = blockIdx.x * 256 + threadIdx.x; // 0 .. 655359, coalesced read
    int k = q / 1280, col = q - k * 1280;
    int gate = col >> 8, hc = col & 255;
    int hcb = hc >> 5, cl = hc & 31;
    int kb = k >> 5, klr = k & 31;
    int ks = klr >> 4, oct = (klr >> 3) & 1, elem = klr & 7;
    size_t off = ((size_t)(hcb * 16 + kb) * 10 + gate * 2 + ks) * 512 +
                 (cl + 32 * oct) * 8 + elem;
    wp[off] = f2h(W[q]);
    if (q < 255 * B) out[OFF_IMASK + q] = 1.0f;
    if (q < L * B) out[OFF_LMASK + q] = 1.0f;
}

// ---------------- fused fp16 32x32x16 MFMA GEMM + LSTM gates ----------------
// 2 waves/block (128 thr). BM=128 rows (64/wave, mf=2) x 160 gate cols (nf=5).
// W: global_load_lds double-buffer (20 KB LDS), shared by both waves.
// A: global->register direct from fragment-major planes (dbl-buffered regs).
// Sync: counted vmcnt + raw s_barrier (T4): kb+1's 9 loads stay in flight.
template <bool PRESPLIT>
__global__ __launch_bounds__(128) void lstm_level_kernel(
    const u16* __restrict__ wp, const float* __restrict__ bias,
    const float* __restrict__ c_prev, float* __restrict__ c_out,
    float* __restrict__ out, int level, const u16* __restrict__ spIn,
    u16* __restrict__ spOut) {
    __shared__ __align__(16) u16 Wld[2][10 * 512]; // 2 x 10 KiB

    const int tid = threadIdx.x;
    const int lane = tid & 63;
    const int wm = tid >> 6; // 0..1
    const int l31 = lane & 31;
    const int lh = lane >> 5;
    const int p = blockIdx.x >> 2;
    const int b0 = (blockIdx.x & 3) * 128;
    const int hcb = blockIdx.y;
    const int hc0 = hcb * 32;

    f32x16 acc[2][5];
#pragma unroll
    for (int nf = 0; nf < 5; ++nf) {
        float bv = bias[nf * H + hc0 + l31];
        f32x16 v;
#pragma unroll
        for (int r = 0; r < 16; ++r) v[r] = bv;
        acc[0][nf] = v;
        acc[1][nf] = v;
    }

    const u16* sL = nullptr;
    const u16* sR = nullptr;
    const float* hL = nullptr;
    const float* hR = nullptr;
    if constexpr (PRESPLIT) {
        sL = spIn + (size_t)(2 * p) * BH;
        sR = sL + BH;
    } else {
        hL = out + OFF_INT + (size_t)postorder_pos(level - 1, 2 * p) * BH;
        hR = out + OFF_INT + (size_t)postorder_pos(level - 1, 2 * p + 1) * BH;
    }

    half8 Af[2][2][2]; // [buf][mf][ks] — all indices compile-time (full unroll)

    // stage kb: issue W DMA (5 per wave) + A reg loads (4 per wave)
    auto stage = [&](int buf, int kb) {
        const u16* wsrc = wp + ((size_t)(hcb * 16 + kb) * 10) * 512;
#pragma unroll
        for (int i = 0; i < 5; ++i) {
            int t = 5 * wm + i;
            gload16(wsrc + t * 512 + lane * 8, &Wld[buf][t * 512]);
        }
#pragma unroll
        for (int mf = 0; mf < 2; ++mf)
#pragma unroll
            for (int ks = 0; ks < 2; ++ks) {
                if constexpr (PRESPLIT) {
                    const u16* pl = (kb < 8) ? sL : sR;
                    int T = ((b0 >> 5) + 2 * wm + mf) * 16 + (kb & 7) * 2 + ks;
                    Af[buf][mf][ks] = *reinterpret_cast<const half8*>(
                        pl + (size_t)T * 512 + lane * 8);
                } else {
                    const float* hsrc = (kb < 8) ? hL : hR;
                    const float* s = hsrc +
                                     (size_t)(b0 + 32 * (2 * wm + mf) + l31) * H +
                                     (kb & 7) * 32 + ks * 16 + lh * 8;
                    float4 v0 = *reinterpret_cast<const float4*>(s);
                    float4 v1 = *reinterpret_cast<const float4*>(s + 4);
                    half8 hv;
                    hv[0] = (_Float16)v0.x; hv[1] = (_Float16)v0.y;
                    hv[2] = (_Float16)v0.z; hv[3] = (_Float16)v0.w;
                    hv[4] = (_Float16)v1.x; hv[5] = (_Float16)v1.y;
                    hv[6] = (_Float16)v1.z; hv[7] = (_Float16)v1.w;
                    Af[buf][mf][ks] = hv;
                }
            }
    };

    stage(0, 0);
#pragma unroll
    for (int kb = 0; kb < 16; ++kb) {
        const int cur = kb & 1;
        if (kb < 15) {
            stage(cur ^ 1, kb + 1);
            // wait own kb loads (9 newer stay in flight), then block barrier
            if constexpr (PRESPLIT)
                asm volatile("s_waitcnt vmcnt(9)" ::: "memory");
            else
                asm volatile("s_waitcnt vmcnt(13)" ::: "memory");
        } else {
            asm volatile("s_waitcnt vmcnt(0)" ::: "memory");
        }
        __builtin_amdgcn_s_barrier();
        __builtin_amdgcn_sched_barrier(0);
#pragma unroll
        for (int ks = 0; ks < 2; ++ks)
#pragma unroll
            for (int nf = 0; nf < 5; ++nf) {
                half8 bf = *reinterpret_cast<const half8*>(
                    &Wld[cur][(nf * 2 + ks) * 512 + lane * 8]);
                acc[0][nf] = __builtin_amdgcn_mfma_f32_32x32x16_f16(
                    Af[cur][0][ks], bf, acc[0][nf], 0, 0, 0);
                acc[1][nf] = __builtin_amdgcn_mfma_f32_32x32x16_f16(
                    Af[cur][1][ks], bf, acc[1][nf], 0, 0, 0);
            }
    }

    // --- epilogue: gates -> c, h; f32 outputs + fp16 plane for next level ---
    const int pout = postorder_pos(level, p);
    float* __restrict__ hout = out + OFF_INT + (size_t)pout * BH;
    const float* cLb = c_prev ? c_prev + (size_t)(2 * p) * BH : nullptr;
    const float* cRb = c_prev ? c_prev + (size_t)(2 * p + 1) * BH : nullptr;
    float* __restrict__ cob = c_out + (size_t)p * BH;
    u16* __restrict__ soH = spOut ? spOut + (size_t)p * BH : nullptr;
    const int hc = hc0 + l31;
    const int kop = hcb * 2 + (l31 >> 4);
    const int lpp = 32 * ((l31 >> 3) & 1);
    const int elp = l31 & 7;

#pragma unroll
    for (int mf = 0; mf < 2; ++mf) {
#pragma unroll
        for (int r = 0; r < 16; ++r) {
            // verified 32x32 C layout: row = (r&3)+8*(r>>2)+4*lh, col = l31
            const int b = b0 + 64 * wm + 32 * mf + 4 * lh + (r & 3) + 8 * (r >> 2);
            float ig = acc[mf][0][r], f1 = acc[mf][1][r], f2 = acc[mf][2][r];
            float og = acc[mf][3][r], ug = acc[mf][4][r];
            float cl = 0.f, cr = 0.f;
            if (c_prev) {
                cl = cLb[(size_t)b * H + hc];
                cr = cRb[(size_t)b * H + hc];
            }
            float c = sigm(ig) * tanhf(ug) + sigm(f1) * cl + sigm(f2) * cr;
            float hval = sigm(og) * tanhf(c);
            cob[(size_t)b * H + hc] = c;
            hout[(size_t)b * H + hc] = hval;
            if (soH) {
                soH[(size_t)((b >> 5) * 16 + kop) * 512 +
                    (size_t)((b & 31) + lpp) * 8 + elp] = f2h(hval);
            }
            if (level == LEVELS) out[OFF_ROOT + (size_t)b * H + hc] = hval;
        }
    }
}

extern "C" void kernel_launch(void* const* d_in, const int* in_sizes, int n_in,
                              void* d_out, int out_size, void* d_ws,
                              size_t ws_size, hipStream_t stream) {
    const int* tok = (const int*)d_in[0];
    const float* emb = (const float*)d_in[1];
    const float* emb_aux = (const float*)d_in[2];
    const float* W = (const float*)d_in[3];
    const float* bias = (const float*)d_in[4];
    float* out = (float*)d_out;

    // ws: cbuf0 | cbuf1 (f32 c ping-pong, 32MB each) | wp (1.31MB fp16 pack)
    //     | spEven (128 planes fp16, 32MB) | spOdd (64 planes, 16MB)
    float* cbuf0 = (float*)d_ws;
    float* cbuf1 = cbuf0 + (size_t)64 * BH;
    u16* wp = (u16*)(cbuf1 + (size_t)64 * BH);
    u16* spEven = wp + (size_t)655360;
    u16* spOdd = spEven + (size_t)128 * BH;
    size_t need = (size_t)((char*)(spOdd + (size_t)64 * BH) - (char*)d_ws);
    const bool presplit = ws_size >= need;

    hipLaunchKernelGGL(wpack_kernel, dim3(2560), dim3(256), 0, stream, W, wp,
                       out);
    hipLaunchKernelGGL(gather_kernel, dim3(L * B / 4), dim3(256), 0, stream,
                       tok, emb, emb_aux, out, spEven, presplit ? 1 : 0);

    for (int level = 1; level <= LEVELS; ++level) {
        int n = L >> level;
        float* c_out = ((level - 1) & 1) ? cbuf1 : cbuf0;
        const float* c_prev =
            (level == 1) ? nullptr : ((level & 1) ? cbuf1 : cbuf0);
        const u16* spIn = (level & 1) ? spEven : spOdd;
        u16* spOutP =
            (level == LEVELS) ? nullptr : ((level & 1) ? spOdd : spEven);
        dim3 grid(4 * n, 8);
        if (presplit) {
            lstm_level_kernel<true><<<grid, dim3(128), 0, stream>>>(
                wp, bias, c_prev, c_out, out, level, spIn, spOutP);
        } else {
            lstm_level_kernel<false><<<grid, dim3(128), 0, stream>>>(
                wp, bias, c_prev, c_out, out, level, nullptr, spOutP);
        }
    }
}

// Round 7
// 350.990 us; speedup vs baseline: 14.7629x; 1.0037x over previous
//
#include <hip/hip_runtime.h>
#include <hip/hip_bf16.h>
#include <hip/hip_fp16.h>
#include <cstdint>
#include <cstddef>

#define H 256
#define L 128
#define B 512
#define LEVELS 7
#define BH (B * H) // 131072

// d_out layout (flat f32 element offsets), return order:
// root[B,H], internal_states[255,B,H], internal_mask[255,B],
// leaves[L,B,H], leaves_aux[L,B,H], leaves_mask[L,B]
#define OFF_ROOT 0
#define OFF_INT (B * H)
#define OFF_IMASK (OFF_INT + 255 * BH)
#define OFF_LEAVES (OFF_IMASK + 255 * B)
#define OFF_LAUX (OFF_LEAVES + L * BH)
#define OFF_LMASK (OFF_LAUX + L * BH)

typedef unsigned short u16;
typedef __attribute__((ext_vector_type(8))) _Float16 half8;
typedef __attribute__((ext_vector_type(16))) float f32x16;

// Fragment-major plane layout (fp16, per node, B x H):
// tile T = (b>>5)*16 + (hc>>4)  (1 KiB = 64 lanes x 16 B)
// lane  = (b&31) + 32*((hc>>3)&1),  elem = hc&7
// -> matches verified 32x32x16 A-frag: row = lane&31, k-oct = lane>>5.

__device__ __forceinline__ int postorder_pos(int level, int j) {
    int start = 0;
    for (int k = level; k <= LEVELS; ++k) {
        if ((j >> (k - level)) & 1) start += (2 << k) - 1;
    }
    return start + (2 << level) - 2;
}

__device__ __forceinline__ float sigm(float x) { return 1.0f / (1.0f + __expf(-x)); }

__device__ __forceinline__ u16 f2h(float x) {
    _Float16 h = (_Float16)x;
    u16 u;
    __builtin_memcpy(&u, &h, 2);
    return u;
}

__device__ __forceinline__ void gload16(const void* g, const void* l) {
    __builtin_amdgcn_global_load_lds(
        (const __attribute__((address_space(1))) void*)g,
        (__attribute__((address_space(3))) void*)l, 16, 0, 0);
}

// ---------------- gather: leaves, aux, level-0 post-order h, leaf planes ----
__global__ __launch_bounds__(256) void gather_kernel(
    const int* __restrict__ tok, const float* __restrict__ emb,
    const float* __restrict__ emb_aux, float* __restrict__ out,
    u16* __restrict__ spLeaf, int do_split) {
    int row = blockIdx.x * 4 + (threadIdx.x >> 6);
    int f4i = threadIdx.x & 63;
    int l = row >> 9, b = row & 511;
    int t = tok[row];
    float4 e = reinterpret_cast<const float4*>(emb + (size_t)t * H)[f4i];
    float4 ea = reinterpret_cast<const float4*>(emb_aux + (size_t)t * H)[f4i];
    reinterpret_cast<float4*>(out + OFF_LEAVES)[(size_t)row * 64 + f4i] = e;
    reinterpret_cast<float4*>(out + OFF_LAUX)[(size_t)row * 64 + f4i] = ea;
    int pp = postorder_pos(0, l);
    reinterpret_cast<float4*>(out + OFF_INT + (size_t)pp * BH + (size_t)b * H)[f4i] = e;
    if (do_split) {
        int ko = f4i >> 2;
        int lanep = (b & 31) + 32 * ((f4i >> 1) & 1);
        int elem0 = 4 * (f4i & 1);
        ushort4 hv;
        hv.x = f2h(e.x); hv.y = f2h(e.y); hv.z = f2h(e.z); hv.w = f2h(e.w);
        u16* np = spLeaf + (size_t)l * BH +
                  (size_t)(((b >> 5) * 16 + ko) * 512 + lanep * 8 + elem0);
        *reinterpret_cast<ushort4*>(np) = hv;
    }
}

// ---------------- W pre-pack into fragment-major fp16 tiles (+ masks) -------
// Pack layout: [hcb=8][kb=16][tile = gate*2 + ks][lane][8], 1 KiB tiles.
// lane = col_local + 32*oct; k = kb*32 + ks*16 + oct*8 + elem.
__global__ __launch_bounds__(256) void wpack_kernel(const float* __restrict__ W,
                                                    u16* __restrict__ wp,
                                                    float* __restrict__ out) {
    int q = blockIdx.x * 256 + threadIdx.x; // 0 .. 655359, coalesced read
    int k = q / 1280, col = q - k * 1280;
    int gate = col >> 8, hc = col & 255;
    int hcb = hc >> 5, cl = hc & 31;
    int kb = k >> 5, klr = k & 31;
    int ks = klr >> 4, oct = (klr >> 3) & 1, elem = klr & 7;
    size_t off = ((size_t)(hcb * 16 + kb) * 10 + gate * 2 + ks) * 512 +
                 (cl + 32 * oct) * 8 + elem;
    wp[off] = f2h(W[q]);
    if (q < 255 * B) out[OFF_IMASK + q] = 1.0f;
    if (q < L * B) out[OFF_LMASK + q] = 1.0f;
}

// ---------------- fused fp16 32x32x16 MFMA GEMM + LSTM gates ----------------
// 2 waves/block (128 thr). BM=128 rows (64/wave, mf=2) x 160 gate cols (nf=5).
// W: global_load_lds double-buffer (20 KB LDS), shared by both waves.
// A: global->register direct from fragment-major planes (dbl-buffered regs).
// Sync per kb (race-free counted pipeline, m218 pattern):
//   stage(kb+1) -> s_waitcnt vmcnt(own kb loads) -> barrier#1 (kb data
//   visible to both waves) -> MFMA(kb) -> barrier#2 (all waves done reading
//   buf -> safe to DMA-overwrite it at kb+1).
template <bool PRESPLIT>
__global__ __launch_bounds__(128) void lstm_level_kernel(
    const u16* __restrict__ wp, const float* __restrict__ bias,
    const float* __restrict__ c_prev, float* __restrict__ c_out,
    float* __restrict__ out, int level, const u16* __restrict__ spIn,
    u16* __restrict__ spOut) {
    __shared__ __align__(16) u16 Wld[2][10 * 512]; // 2 x 10 KiB

    const int tid = threadIdx.x;
    const int lane = tid & 63;
    const int wm = tid >> 6; // 0..1
    const int l31 = lane & 31;
    const int lh = lane >> 5;
    const int p = blockIdx.x >> 2;
    const int b0 = (blockIdx.x & 3) * 128;
    const int hcb = blockIdx.y;
    const int hc0 = hcb * 32;

    f32x16 acc[2][5];
#pragma unroll
    for (int nf = 0; nf < 5; ++nf) {
        float bv = bias[nf * H + hc0 + l31];
        f32x16 v;
#pragma unroll
        for (int r = 0; r < 16; ++r) v[r] = bv;
        acc[0][nf] = v;
        acc[1][nf] = v;
    }

    const u16* sL = nullptr;
    const u16* sR = nullptr;
    const float* hL = nullptr;
    const float* hR = nullptr;
    if constexpr (PRESPLIT) {
        sL = spIn + (size_t)(2 * p) * BH;
        sR = sL + BH;
    } else {
        hL = out + OFF_INT + (size_t)postorder_pos(level - 1, 2 * p) * BH;
        hR = out + OFF_INT + (size_t)postorder_pos(level - 1, 2 * p + 1) * BH;
    }

    half8 Af[2][2][2]; // [buf][mf][ks] — all indices compile-time (full unroll)

    // stage kb: issue W DMA (5 per wave) + A reg loads (4 per wave)
    auto stage = [&](int buf, int kb) {
        const u16* wsrc = wp + ((size_t)(hcb * 16 + kb) * 10) * 512;
#pragma unroll
        for (int i = 0; i < 5; ++i) {
            int t = 5 * wm + i;
            gload16(wsrc + t * 512 + lane * 8, &Wld[buf][t * 512]);
        }
#pragma unroll
        for (int mf = 0; mf < 2; ++mf)
#pragma unroll
            for (int ks = 0; ks < 2; ++ks) {
                if constexpr (PRESPLIT) {
                    const u16* pl = (kb < 8) ? sL : sR;
                    int T = ((b0 >> 5) + 2 * wm + mf) * 16 + (kb & 7) * 2 + ks;
                    Af[buf][mf][ks] = *reinterpret_cast<const half8*>(
                        pl + (size_t)T * 512 + lane * 8);
                } else {
                    const float* hsrc = (kb < 8) ? hL : hR;
                    const float* s = hsrc +
                                     (size_t)(b0 + 32 * (2 * wm + mf) + l31) * H +
                                     (kb & 7) * 32 + ks * 16 + lh * 8;
                    float4 v0 = *reinterpret_cast<const float4*>(s);
                    float4 v1 = *reinterpret_cast<const float4*>(s + 4);
                    half8 hv;
                    hv[0] = (_Float16)v0.x; hv[1] = (_Float16)v0.y;
                    hv[2] = (_Float16)v0.z; hv[3] = (_Float16)v0.w;
                    hv[4] = (_Float16)v1.x; hv[5] = (_Float16)v1.y;
                    hv[6] = (_Float16)v1.z; hv[7] = (_Float16)v1.w;
                    Af[buf][mf][ks] = hv;
                }
            }
    };

    stage(0, 0);
#pragma unroll
    for (int kb = 0; kb < 16; ++kb) {
        const int cur = kb & 1;
        if (kb < 15) {
            stage(cur ^ 1, kb + 1);
            // wait own kb loads only (kb+1's stay in flight across barrier)
            if constexpr (PRESPLIT)
                asm volatile("s_waitcnt vmcnt(9)" ::: "memory");
            else
                asm volatile("s_waitcnt vmcnt(13)" ::: "memory");
        } else {
            asm volatile("s_waitcnt vmcnt(0)" ::: "memory");
        }
        __builtin_amdgcn_s_barrier(); // #1: all kb W tiles visible in LDS
        __builtin_amdgcn_sched_barrier(0);
#pragma unroll
        for (int ks = 0; ks < 2; ++ks)
#pragma unroll
            for (int nf = 0; nf < 5; ++nf) {
                half8 bf = *reinterpret_cast<const half8*>(
                    &Wld[cur][(nf * 2 + ks) * 512 + lane * 8]);
                acc[0][nf] = __builtin_amdgcn_mfma_f32_32x32x16_f16(
                    Af[cur][0][ks], bf, acc[0][nf], 0, 0, 0);
                acc[1][nf] = __builtin_amdgcn_mfma_f32_32x32x16_f16(
                    Af[cur][1][ks], bf, acc[1][nf], 0, 0, 0);
            }
        // #2: recycle protection — Wld[cur] is DMA-overwritten at kb+1;
        // every wave's ds_reads of it completed (consumed by MFMA above).
        if (kb < 15) __builtin_amdgcn_s_barrier();
    }

    // --- epilogue: gates -> c, h; f32 outputs + fp16 plane for next level ---
    const int pout = postorder_pos(level, p);
    float* __restrict__ hout = out + OFF_INT + (size_t)pout * BH;
    const float* cLb = c_prev ? c_prev + (size_t)(2 * p) * BH : nullptr;
    const float* cRb = c_prev ? c_prev + (size_t)(2 * p + 1) * BH : nullptr;
    float* __restrict__ cob = c_out + (size_t)p * BH;
    u16* __restrict__ soH = spOut ? spOut + (size_t)p * BH : nullptr;
    const int hc = hc0 + l31;
    const int kop = hcb * 2 + (l31 >> 4);
    const int lpp = 32 * ((l31 >> 3) & 1);
    const int elp = l31 & 7;

#pragma unroll
    for (int mf = 0; mf < 2; ++mf) {
#pragma unroll
        for (int r = 0; r < 16; ++r) {
            // verified 32x32 C layout: row = (r&3)+8*(r>>2)+4*lh, col = l31
            const int b = b0 + 64 * wm + 32 * mf + 4 * lh + (r & 3) + 8 * (r >> 2);
            float ig = acc[mf][0][r], f1 = acc[mf][1][r], f2 = acc[mf][2][r];
            float og = acc[mf][3][r], ug = acc[mf][4][r];
            float cl = 0.f, cr = 0.f;
            if (c_prev) {
                cl = cLb[(size_t)b * H + hc];
                cr = cRb[(size_t)b * H + hc];
            }
            float c = sigm(ig) * tanhf(ug) + sigm(f1) * cl + sigm(f2) * cr;
            float hval = sigm(og) * tanhf(c);
            cob[(size_t)b * H + hc] = c;
            hout[(size_t)b * H + hc] = hval;
            if (soH) {
                soH[(size_t)((b >> 5) * 16 + kop) * 512 +
                    (size_t)((b & 31) + lpp) * 8 + elp] = f2h(hval);
            }
            if (level == LEVELS) out[OFF_ROOT + (size_t)b * H + hc] = hval;
        }
    }
}

extern "C" void kernel_launch(void* const* d_in, const int* in_sizes, int n_in,
                              void* d_out, int out_size, void* d_ws,
                              size_t ws_size, hipStream_t stream) {
    const int* tok = (const int*)d_in[0];
    const float* emb = (const float*)d_in[1];
    const float* emb_aux = (const float*)d_in[2];
    const float* W = (const float*)d_in[3];
    const float* bias = (const float*)d_in[4];
    float* out = (float*)d_out;

    // ws: cbuf0 | cbuf1 (f32 c ping-pong, 32MB each) | wp (1.31MB fp16 pack)
    //     | spEven (128 planes fp16, 32MB) | spOdd (64 planes, 16MB)
    float* cbuf0 = (float*)d_ws;
    float* cbuf1 = cbuf0 + (size_t)64 * BH;
    u16* wp = (u16*)(cbuf1 + (size_t)64 * BH);
    u16* spEven = wp + (size_t)655360;
    u16* spOdd = spEven + (size_t)128 * BH;
    size_t need = (size_t)((char*)(spOdd + (size_t)64 * BH) - (char*)d_ws);
    const bool presplit = ws_size >= need;

    hipLaunchKernelGGL(wpack_kernel, dim3(2560), dim3(256), 0, stream, W, wp,
                       out);
    hipLaunchKernelGGL(gather_kernel, dim3(L * B / 4), dim3(256), 0, stream,
                       tok, emb, emb_aux, out, spEven, presplit ? 1 : 0);

    for (int level = 1; level <= LEVELS; ++level) {
        int n = L >> level;
        float* c_out = ((level - 1) & 1) ? cbuf1 : cbuf0;
        const float* c_prev =
            (level == 1) ? nullptr : ((level & 1) ? cbuf1 : cbuf0);
        const u16* spIn = (level & 1) ? spEven : spOdd;
        u16* spOutP =
            (level == LEVELS) ? nullptr : ((level & 1) ? spOdd : spEven);
        dim3 grid(4 * n, 8);
        if (presplit) {
            lstm_level_kernel<true><<<grid, dim3(128), 0, stream>>>(
                wp, bias, c_prev, c_out, out, level, spIn, spOutP);
        } else {
            lstm_level_kernel<false><<<grid, dim3(128), 0, stream>>>(
                wp, bias, c_prev, c_out, out, level, nullptr, spOutP);
        }
    }
}